// Round 5
// baseline (326.397 us; speedup 1.0000x reference)
//
#include <hip/hip_runtime.h>
#include <stdint.h>

#define EPSV 1e-5f

typedef __attribute__((ext_vector_type(8))) short short8;
typedef __attribute__((ext_vector_type(4))) float floatx4;
typedef __attribute__((ext_vector_type(2))) float float2v;

__device__ __forceinline__ unsigned short f2bf(float f) {
    union { float f; uint32_t u; } v; v.f = f;
    uint32_t u = v.u;
    return (unsigned short)((u + 0x7FFFu + ((u >> 16) & 1u)) >> 16);  // RNE
}

// ---- kernel 1: depthwise 3x3 + BN1 + ReLU + exact fp32 prune -> y bf16 [b][c][n]
//      NEW: pruned (b,c) planes are NOT stored (poison stays in y_ws); a per-
//      (b,c) keep flag tells k_pw to substitute zeros without reading.
__global__ __launch_bounds__(256) void k_dw(
        const float* __restrict__ x, const float* __restrict__ dw_w,
        const float* __restrict__ dw_b, const float* __restrict__ g1,
        const float* __restrict__ b1, const float* __restrict__ m1,
        const float* __restrict__ v1,
        const float* __restrict__ pw_w, const float* __restrict__ pw_b,
        const float* __restrict__ g2, const float* __restrict__ b2,
        const float* __restrict__ m2, const float* __restrict__ v2,
        unsigned short* __restrict__ y_ws,
        unsigned short* __restrict__ w_bf, float* __restrict__ bias2,
        float* __restrict__ keep) {
    const int c = blockIdx.x, b = blockIdx.y;
    const int t = threadIdx.x;
    __shared__ __align__(16) float halo_buf[4 + 58 * 60];  // 4-float front pad
    __shared__ float red[4];
    float* halo = halo_buf + 4;

    if (b == 0) {   // fused weight-fold with K-slot permutation
        int idx = c * 256 + t;
        int o = idx >> 7, s = idx & 127;
        int csrc = ((s >> 5) << 2) + ((s >> 3) & 3) + ((s & 7) << 4);
        float inv = g2[o] / sqrtf(v2[o] + EPSV);
        w_bf[idx] = f2bf(pw_w[o * 128 + csrc] * inv);
        if (s == 0) bias2[o] = pw_b[o] * inv + b2[o] - m2[o] * inv;
    }

    const float* xs = x + (size_t)(b * 128 + c) * 3136;

    // border zeros: row 0 (15 f4), row 57 (15 f4), cols 56..59 rows 1..56 (56 f4),
    // and the 4-float front pad (serves halo[-1] for row 0).
    {
        floatx4 zz = {0.f, 0.f, 0.f, 0.f};
        if (t < 15)       *(floatx4*)(halo + 4 * t) = zz;                  // row 0
        else if (t < 30)  *(floatx4*)(halo + 57 * 60 + 4 * (t - 15)) = zz; // row 57
        else if (t < 86)  *(floatx4*)(halo + (t - 29) * 60 + 56) = zz;     // right pad
        else if (t == 86) *(floatx4*)halo_buf = zz;                        // front pad
    }
    // interior: 784 float4 loads -> single aligned b128 LDS writes
    {
        const floatx4* x4 = (const floatx4*)xs;
        #pragma unroll
        for (int i = 0; i < 4; ++i) {
            int f = t + 256 * i;
            if (f < 784) {
                floatx4 v = x4[f];
                int p = 4 * f;
                int h = p / 56, ww = p - h * 56;
                *(floatx4*)(halo + (h + 1) * 60 + ww) = v;   // 16B aligned
            }
        }
    }
    const float* wk = dw_w + c * 9;
    float k0 = wk[0], k1 = wk[1], k2 = wk[2], k3 = wk[3], k4 = wk[4],
          k5 = wk[5], k6 = wk[6], k7 = wk[7], k8 = wk[8];
    float inv1 = g1[c] / sqrtf(v1[c] + EPSV);                 // exact, matches ref
    float add0 = dw_b[c] * inv1 + b1[c] - m1[c] * inv1;
    __syncthreads();

    // 392 groups of 8 outputs (56 rows x 7 groups); thread t does g = t, t+256
    float yv[16];
    float mx = 0.f;
    #pragma unroll
    for (int gi = 0; gi < 2; ++gi) {
        int g = t + gi * 256;
        if (g < 392) {
            int gh = g / 7, gw = (g - gh * 7) * 8;
            const float* p0 = halo + gh * 60 + gw;
            float w0[10], w1[10], w2[10];
#define LOADROW(dst, p) { \
            float2v L_ = *(const float2v*)((p) - 2); \
            floatx4 M0_ = *(const floatx4*)(p); \
            floatx4 M1_ = *(const floatx4*)((p) + 4); \
            float2v R_ = *(const float2v*)((p) + 8); \
            dst[0] = L_[1]; \
            dst[1] = M0_[0]; dst[2] = M0_[1]; dst[3] = M0_[2]; dst[4] = M0_[3]; \
            dst[5] = M1_[0]; dst[6] = M1_[1]; dst[7] = M1_[2]; dst[8] = M1_[3]; \
            dst[9] = R_[0]; }
            LOADROW(w0, p0)
            LOADROW(w1, p0 + 60)
            LOADROW(w2, p0 + 120)
#undef LOADROW
            #pragma unroll
            for (int j = 0; j < 8; ++j) {
                float s = k0 * w0[j] + k1 * w0[j + 1] + k2 * w0[j + 2]
                        + k3 * w1[j] + k4 * w1[j + 1] + k5 * w1[j + 2]
                        + k6 * w2[j] + k7 * w2[j + 1] + k8 * w2[j + 2];
                float yy = fmaxf(s * inv1 + add0, 0.f);
                mx = fmaxf(mx, yy);
                yv[gi * 8 + j] = yy;
            }
        }
    }
    #pragma unroll
    for (int off = 32; off; off >>= 1) mx = fmaxf(mx, __shfl_xor(mx, off));
    if ((t & 63) == 0) red[t >> 6] = mx;
    __syncthreads();
    float m4 = fmaxf(fmaxf(red[0], red[1]), fmaxf(red[2], red[3]));
    const bool kept = (m4 >= 4.0f);           // DW_THR, exact fp32 decision

    if (t == 0) keep[b * 128 + c] = kept ? 1.f : 0.f;

    if (kept) {                               // block-uniform: skip stores+pack
        unsigned short* yo = y_ws + (size_t)(b * 128 + c) * 3136;
        #pragma unroll
        for (int gi = 0; gi < 2; ++gi) {
            int g = t + gi * 256;
            if (g < 392) {
                uint4 pkv;
                uint32_t pk[4];
                #pragma unroll
                for (int j2 = 0; j2 < 4; ++j2) {
                    unsigned short h0 = f2bf(yv[gi * 8 + 2 * j2]);
                    unsigned short h1 = f2bf(yv[gi * 8 + 2 * j2 + 1]);
                    pk[j2] = (uint32_t)h0 | ((uint32_t)h1 << 16);
                }
                pkv.x = pk[0]; pkv.y = pk[1]; pkv.z = pk[2]; pkv.w = pk[3];
                *(uint4*)(yo + g * 8) = pkv;   // 16B aligned, lanes contiguous
            }
        }
    }
}

// ---- kernel 2: pointwise GEMM, operand-swapped mfma(A=y_frag, B=w_frag)
//      -> D[row=n][col=o]. Staging loads are keep-flag predicated: pruned
//      channels stay zero-init and their (poisoned) y planes are never read.
//      Epilogue: wave-private LDS restage (b128, XOR swizzle) + 512B-contiguous
//      nontemporal dwordx4 z stores (round-2/4 proven pattern).
__global__ __launch_bounds__(256, 2) void k_pw(
        const unsigned short* __restrict__ y,     // [b][c][3136] bf16
        const unsigned short* __restrict__ w_bf,  // [o][s] bf16, K-permuted
        const float* __restrict__ bias2, const float* __restrict__ keep,
        float* __restrict__ z) {
    const int nt = blockIdx.x;   // 25 N-tiles of 128 (last is half)
    const int b  = blockIdx.y;   // 64 batches
    const int t = threadIdx.x;
    const int w = t >> 6, lane = t & 63;
    const int q = lane >> 4, r = lane & 15;
    __shared__ __align__(16) char smem[36864];    // B_s, then reused as E
    short* B_s = (short*)smem;

    // weight fragments (B operand): wave w owns o in [w*64, w*64+64);
    // slot j holds w[o = ...+r][c = kk*4 + q + 16*j] (permuted w_bf)
    short8 wf[4][4];
    #pragma unroll
    for (int it = 0; it < 4; ++it)
        #pragma unroll
        for (int kk = 0; kk < 4; ++kk)
            wf[it][kk] = *(const short8*)(w_bf +
                (size_t)(w * 64 + it * 16 + r) * 128 + kk * 32 + q * 8);

    // stage: thread t loads y[c = t>>4 + 16i][nb..nb+8), nb=(t&15)*8 (coalesced),
    // register-transposes to W[j] = {y[t>>4 + 16e][nb+j]}, writes b128.
    // Layout: B_s[n][slot'][e], pitch 144 shorts; slot' = slot ^ (n>>3).
    {
        const int n0g = nt * 128;
        const int nb = (t & 15) * 8;
        const bool valid = (n0g + nb < 3136);      // chunks fully valid or out
        const float* kb = keep + b * 128;
        uint32_t Vd[8][4];
        const unsigned short* yb = y + (size_t)(b * 128) * 3136 + n0g + nb;
        #pragma unroll
        for (int i = 0; i < 8; ++i) {
            int cc = (t >> 4) + i * 16;
            uint4 v = make_uint4(0u, 0u, 0u, 0u);
            if (valid && kb[cc] != 0.f)            // pruned plane: keep zeros,
                v = *(const uint4*)(yb + (size_t)cc * 3136);  // never touch poison
            Vd[i][0] = v.x; Vd[i][1] = v.y; Vd[i][2] = v.z; Vd[i][3] = v.w;
        }
        const int slot_w = (t >> 4) ^ (t & 15);    // ^ (n>>3), n>>3 == t&15
        #pragma unroll
        for (int j = 0; j < 8; ++j) {
            const int sh = (j & 1) * 16;
            uint32_t Wd[4];
            #pragma unroll
            for (int k2 = 0; k2 < 4; ++k2) {
                uint32_t lo = (Vd[2 * k2][j >> 1] >> sh) & 0xffffu;
                uint32_t hi = (Vd[2 * k2 + 1][j >> 1] >> sh) & 0xffffu;
                Wd[k2] = lo | (hi << 16);
            }
            uint4 wv; wv.x = Wd[0]; wv.y = Wd[1]; wv.z = Wd[2]; wv.w = Wd[3];
            *(uint4*)&B_s[(nb + j) * 144 + slot_w * 8] = wv;
        }
    }
    __syncthreads();

    floatx4 acc[4][8];
    #pragma unroll
    for (int i = 0; i < 4; ++i)
        #pragma unroll
        for (int j = 0; j < 8; ++j) acc[i][j] = (floatx4)0.f;

    #pragma unroll
    for (int kk = 0; kk < 4; ++kk) {               // K = 128 = 4 x 32
        short8 yf[8];                              // A operand: y[n][c] frags
        #pragma unroll
        for (int jt = 0; jt < 8; ++jt) {
            int nl = jt * 16 + r;
            int slot_r = (kk * 4 + q) ^ (nl >> 3);
            yf[jt] = *(const short8*)&B_s[nl * 144 + slot_r * 8];
        }
        #pragma unroll
        for (int it = 0; it < 4; ++it)
            #pragma unroll
            for (int jt = 0; jt < 8; ++jt)
                acc[it][jt] = __builtin_amdgcn_mfma_f32_16x16x32_bf16(
                    yf[jt], wf[it][kk], acc[it][jt], 0, 0, 0);
    }

    // epilogue: restage via wave-private LDS (writer: row r, unit u=4*jt+q,
    // swizzle u^(r&7); reader: half-wave per row rho, 512B-contiguous stores).
    __syncthreads();                               // B_s dead -> reuse as E
    char* Ew = smem + w * 8192;                    // wave-private 16 x 512B
    const int n_base = nt * 128;
    float* zb = z + (size_t)b * 256 * 3136;
    #pragma unroll
    for (int it = 0; it < 4; ++it) {
        float bv = bias2[w * 64 + it * 16 + r];
        #pragma unroll
        for (int jt = 0; jt < 8; ++jt) {
            floatx4 v;
            v[0] = fmaxf(acc[it][jt][0] + bv, 0.f);
            v[1] = fmaxf(acc[it][jt][1] + bv, 0.f);
            v[2] = fmaxf(acc[it][jt][2] + bv, 0.f);
            v[3] = fmaxf(acc[it][jt][3] + bv, 0.f);
            *(floatx4*)(Ew + r * 512 + ((4 * jt + q) ^ (r & 7)) * 16) = v;
        }
        asm volatile("s_waitcnt lgkmcnt(0)" ::: "memory");   // writes visible
        __builtin_amdgcn_sched_barrier(0);
        #pragma unroll
        for (int s = 0; s < 8; ++s) {
            int rho = s * 2 + (lane >> 5);
            int u = lane & 31, n4 = u * 4;
            if (n_base + n4 < 3136) {
                floatx4 v = *(const floatx4*)(Ew + rho * 512 + ((u ^ (rho & 7)) * 16));
                int o = w * 64 + it * 16 + rho;
                __builtin_nontemporal_store(v,
                    (floatx4*)(zb + (size_t)o * 3136 + n_base + n4));
            }
        }
        asm volatile("s_waitcnt lgkmcnt(0)" ::: "memory");   // reads done before
        __builtin_amdgcn_sched_barrier(0);                   // next it's writes
    }
}

extern "C" void kernel_launch(void* const* d_in, const int* in_sizes, int n_in,
                              void* d_out, int out_size, void* d_ws, size_t ws_size,
                              hipStream_t stream) {
    const float* x    = (const float*)d_in[0];
    const float* dw_w = (const float*)d_in[1];
    const float* dw_b = (const float*)d_in[2];
    const float* g1   = (const float*)d_in[3];
    const float* b1   = (const float*)d_in[4];
    const float* m1   = (const float*)d_in[5];
    const float* v1   = (const float*)d_in[6];
    const float* pw_w = (const float*)d_in[7];
    const float* pw_b = (const float*)d_in[8];
    const float* g2   = (const float*)d_in[9];
    const float* b2   = (const float*)d_in[10];
    const float* m2   = (const float*)d_in[11];
    const float* v2   = (const float*)d_in[12];
    float* z = (float*)d_out;

    // ws layout: y bf16 51,380,224 B | w_bf 65,536 B | bias2 1,024 B | keep 32,768 B
    const size_t YB = 51380224;
    unsigned short* y_ws = (unsigned short*)d_ws;
    unsigned short* w_bf = (unsigned short*)((char*)d_ws + YB);
    float* bias2         = (float*)((char*)d_ws + YB + 65536);
    float* keep          = (float*)((char*)d_ws + YB + 65536 + 1024);

    hipLaunchKernelGGL(k_dw, dim3(128, 64), dim3(256), 0, stream,
                       x, dw_w, dw_b, g1, b1, m1, v1,
                       pw_w, pw_b, g2, b2, m2, v2, y_ws, w_bf, bias2, keep);
    hipLaunchKernelGGL(k_pw, dim3(25, 64), dim3(256), 0, stream,
                       y_ws, w_bf, bias2, keep, z);
}

// Round 8
// 313.897 us; speedup vs baseline: 1.0398x; 1.0398x over previous
//
#include <hip/hip_runtime.h>
#include <stdint.h>

#define EPSV 1e-5f

typedef __attribute__((ext_vector_type(8))) short short8;
typedef __attribute__((ext_vector_type(4))) float floatx4;
typedef __attribute__((ext_vector_type(2))) float float2v;

__device__ __forceinline__ unsigned short f2bf(float f) {
    union { float f; uint32_t u; } v; v.f = f;
    uint32_t u = v.u;
    return (unsigned short)((u + 0x7FFFu + ((u >> 16) & 1u)) >> 16);  // RNE
}

// ---- kernel 1: depthwise 3x3 + BN1 + ReLU + exact fp32 prune -> y bf16 [b][c][n]
//      (byte-identical to round 5 — attribution isolation)
__global__ __launch_bounds__(256) void k_dw(
        const float* __restrict__ x, const float* __restrict__ dw_w,
        const float* __restrict__ dw_b, const float* __restrict__ g1,
        const float* __restrict__ b1, const float* __restrict__ m1,
        const float* __restrict__ v1,
        const float* __restrict__ pw_w, const float* __restrict__ pw_b,
        const float* __restrict__ g2, const float* __restrict__ b2,
        const float* __restrict__ m2, const float* __restrict__ v2,
        unsigned short* __restrict__ y_ws,
        unsigned short* __restrict__ w_bf, float* __restrict__ bias2,
        float* __restrict__ keep) {
    const int c = blockIdx.x, b = blockIdx.y;
    const int t = threadIdx.x;
    __shared__ __align__(16) float halo_buf[4 + 58 * 60];  // 4-float front pad
    __shared__ float red[4];
    float* halo = halo_buf + 4;

    if (b == 0) {   // fused weight-fold with K-slot permutation
        int idx = c * 256 + t;
        int o = idx >> 7, s = idx & 127;
        int csrc = ((s >> 5) << 2) + ((s >> 3) & 3) + ((s & 7) << 4);
        float inv = g2[o] / sqrtf(v2[o] + EPSV);
        w_bf[idx] = f2bf(pw_w[o * 128 + csrc] * inv);
        if (s == 0) bias2[o] = pw_b[o] * inv + b2[o] - m2[o] * inv;
    }

    const float* xs = x + (size_t)(b * 128 + c) * 3136;

    {
        floatx4 zz = {0.f, 0.f, 0.f, 0.f};
        if (t < 15)       *(floatx4*)(halo + 4 * t) = zz;                  // row 0
        else if (t < 30)  *(floatx4*)(halo + 57 * 60 + 4 * (t - 15)) = zz; // row 57
        else if (t < 86)  *(floatx4*)(halo + (t - 29) * 60 + 56) = zz;     // right pad
        else if (t == 86) *(floatx4*)halo_buf = zz;                        // front pad
    }
    {
        const floatx4* x4 = (const floatx4*)xs;
        #pragma unroll
        for (int i = 0; i < 4; ++i) {
            int f = t + 256 * i;
            if (f < 784) {
                floatx4 v = x4[f];
                int p = 4 * f;
                int h = p / 56, ww = p - h * 56;
                *(floatx4*)(halo + (h + 1) * 60 + ww) = v;   // 16B aligned
            }
        }
    }
    const float* wk = dw_w + c * 9;
    float k0 = wk[0], k1 = wk[1], k2 = wk[2], k3 = wk[3], k4 = wk[4],
          k5 = wk[5], k6 = wk[6], k7 = wk[7], k8 = wk[8];
    float inv1 = g1[c] / sqrtf(v1[c] + EPSV);                 // exact, matches ref
    float add0 = dw_b[c] * inv1 + b1[c] - m1[c] * inv1;
    __syncthreads();

    float yv[16];
    float mx = 0.f;
    #pragma unroll
    for (int gi = 0; gi < 2; ++gi) {
        int g = t + gi * 256;
        if (g < 392) {
            int gh = g / 7, gw = (g - gh * 7) * 8;
            const float* p0 = halo + gh * 60 + gw;
            float w0[10], w1[10], w2[10];
#define LOADROW(dst, p) { \
            float2v L_ = *(const float2v*)((p) - 2); \
            floatx4 M0_ = *(const floatx4*)(p); \
            floatx4 M1_ = *(const floatx4*)((p) + 4); \
            float2v R_ = *(const float2v*)((p) + 8); \
            dst[0] = L_[1]; \
            dst[1] = M0_[0]; dst[2] = M0_[1]; dst[3] = M0_[2]; dst[4] = M0_[3]; \
            dst[5] = M1_[0]; dst[6] = M1_[1]; dst[7] = M1_[2]; dst[8] = M1_[3]; \
            dst[9] = R_[0]; }
            LOADROW(w0, p0)
            LOADROW(w1, p0 + 60)
            LOADROW(w2, p0 + 120)
#undef LOADROW
            #pragma unroll
            for (int j = 0; j < 8; ++j) {
                float s = k0 * w0[j] + k1 * w0[j + 1] + k2 * w0[j + 2]
                        + k3 * w1[j] + k4 * w1[j + 1] + k5 * w1[j + 2]
                        + k6 * w2[j] + k7 * w2[j + 1] + k8 * w2[j + 2];
                float yy = fmaxf(s * inv1 + add0, 0.f);
                mx = fmaxf(mx, yy);
                yv[gi * 8 + j] = yy;
            }
        }
    }
    #pragma unroll
    for (int off = 32; off; off >>= 1) mx = fmaxf(mx, __shfl_xor(mx, off));
    if ((t & 63) == 0) red[t >> 6] = mx;
    __syncthreads();
    float m4 = fmaxf(fmaxf(red[0], red[1]), fmaxf(red[2], red[3]));
    const bool kept = (m4 >= 4.0f);           // DW_THR, exact fp32 decision

    if (t == 0) keep[b * 128 + c] = kept ? 1.f : 0.f;

    if (kept) {                               // block-uniform: skip stores+pack
        unsigned short* yo = y_ws + (size_t)(b * 128 + c) * 3136;
        #pragma unroll
        for (int gi = 0; gi < 2; ++gi) {
            int g = t + gi * 256;
            if (g < 392) {
                uint4 pkv;
                uint32_t pk[4];
                #pragma unroll
                for (int j2 = 0; j2 < 4; ++j2) {
                    unsigned short h0 = f2bf(yv[gi * 8 + 2 * j2]);
                    unsigned short h1 = f2bf(yv[gi * 8 + 2 * j2 + 1]);
                    pk[j2] = (uint32_t)h0 | ((uint32_t)h1 << 16);
                }
                pkv.x = pk[0]; pkv.y = pk[1]; pkv.z = pk[2]; pkv.w = pk[3];
                *(uint4*)(yo + g * 8) = pkv;   // 16B aligned, lanes contiguous
            }
        }
    }
}

// ---- kernel 2: pointwise GEMM, operand-swapped mfma(A=y_frag, B=w_frag).
//      OCCUPANCY EXPERIMENT, de-risked: per-wave tile halved (32 o x 128 n,
//      acc 64 VGPR), o-range split across blockIdx.z, wf loads after staging.
//      NO explicit min-waves launch bound (compile-risk removed): natural
//      VGPR allocation (~160) should land 3 blocks/CU by itself.
//      Staging + MFMA + epilogue logic identical to the round-4/5 proven code.
__global__ __launch_bounds__(256) void k_pw(
        const unsigned short* __restrict__ y,     // [b][c][3136] bf16
        const unsigned short* __restrict__ w_bf,  // [o][s] bf16, K-permuted
        const float* __restrict__ bias2, const float* __restrict__ keep,
        float* __restrict__ z) {
    const int nt = blockIdx.x;   // 25 N-tiles of 128 (last is half)
    const int b  = blockIdx.y;   // 64 batches
    const int oh = blockIdx.z;   // o-half: [oh*128, oh*128+128)
    const int t = threadIdx.x;
    const int w = t >> 6, lane = t & 63;
    const int q = lane >> 4, r = lane & 15;
    __shared__ __align__(16) char smem[36864];    // B_s, then reused as E
    short* B_s = (short*)smem;

    // stage: thread t loads y[c = t>>4 + 16i][nb..nb+8), nb=(t&15)*8 (coalesced),
    // register-transposes to W[j] = {y[t>>4 + 16e][nb+j]}, writes b128.
    // Layout: B_s[n][slot'][e], pitch 144 shorts; slot' = slot ^ (n>>3).
    {
        const int n0g = nt * 128;
        const int nb = (t & 15) * 8;
        const bool valid = (n0g + nb < 3136);      // chunks fully valid or out
        const float* kb = keep + b * 128;
        uint32_t Vd[8][4];
        const unsigned short* yb = y + (size_t)(b * 128) * 3136 + n0g + nb;
        #pragma unroll
        for (int i = 0; i < 8; ++i) {
            int cc = (t >> 4) + i * 16;
            uint4 v = make_uint4(0u, 0u, 0u, 0u);
            if (valid && kb[cc] != 0.f)            // pruned plane: keep zeros,
                v = *(const uint4*)(yb + (size_t)cc * 3136);  // never touch poison
            Vd[i][0] = v.x; Vd[i][1] = v.y; Vd[i][2] = v.z; Vd[i][3] = v.w;
        }
        const int slot_w = (t >> 4) ^ (t & 15);    // ^ (n>>3), n>>3 == t&15
        #pragma unroll
        for (int j = 0; j < 8; ++j) {
            const int sh = (j & 1) * 16;
            uint32_t Wd[4];
            #pragma unroll
            for (int k2 = 0; k2 < 4; ++k2) {
                uint32_t lo = (Vd[2 * k2][j >> 1] >> sh) & 0xffffu;
                uint32_t hi = (Vd[2 * k2 + 1][j >> 1] >> sh) & 0xffffu;
                Wd[k2] = lo | (hi << 16);
            }
            uint4 wv; wv.x = Wd[0]; wv.y = Wd[1]; wv.z = Wd[2]; wv.w = Wd[3];
            *(uint4*)&B_s[(nb + j) * 144 + slot_w * 8] = wv;
        }
    }

    // weight fragments (B operand), loaded after staging to cut peak VGPR:
    // wave w owns o in [oh*128 + w*32, +32); slot j holds w[o][c=kk*4+q+16j]
    short8 wf[2][4];
    #pragma unroll
    for (int it = 0; it < 2; ++it)
        #pragma unroll
        for (int kk = 0; kk < 4; ++kk)
            wf[it][kk] = *(const short8*)(w_bf +
                (size_t)(oh * 128 + w * 32 + it * 16 + r) * 128 + kk * 32 + q * 8);

    __syncthreads();

    floatx4 acc[2][8];
    #pragma unroll
    for (int i = 0; i < 2; ++i)
        #pragma unroll
        for (int j = 0; j < 8; ++j) acc[i][j] = (floatx4)0.f;

    #pragma unroll
    for (int kk = 0; kk < 4; ++kk) {               // K = 128 = 4 x 32
        short8 yf[8];                              // A operand: y[n][c] frags
        #pragma unroll
        for (int jt = 0; jt < 8; ++jt) {
            int nl = jt * 16 + r;
            int slot_r = (kk * 4 + q) ^ (nl >> 3);
            yf[jt] = *(const short8*)&B_s[nl * 144 + slot_r * 8];
        }
        #pragma unroll
        for (int it = 0; it < 2; ++it)
            #pragma unroll
            for (int jt = 0; jt < 8; ++jt)
                acc[it][jt] = __builtin_amdgcn_mfma_f32_16x16x32_bf16(
                    yf[jt], wf[it][kk], acc[it][jt], 0, 0, 0);
    }

    // epilogue: restage via wave-private LDS (writer: row r, unit u=4*jt+q,
    // swizzle u^(r&7); reader: half-wave per row rho, 512B-contiguous stores).
    __syncthreads();                               // B_s dead -> reuse as E
    char* Ew = smem + w * 8192;                    // wave-private 16 x 512B
    const int n_base = nt * 128;
    const int o_base = oh * 128 + w * 32;
    float* zb = z + (size_t)b * 256 * 3136;
    #pragma unroll
    for (int it = 0; it < 2; ++it) {
        float bv = bias2[o_base + it * 16 + r];
        #pragma unroll
        for (int jt = 0; jt < 8; ++jt) {
            floatx4 v;
            v[0] = fmaxf(acc[it][jt][0] + bv, 0.f);
            v[1] = fmaxf(acc[it][jt][1] + bv, 0.f);
            v[2] = fmaxf(acc[it][jt][2] + bv, 0.f);
            v[3] = fmaxf(acc[it][jt][3] + bv, 0.f);
            *(floatx4*)(Ew + r * 512 + ((4 * jt + q) ^ (r & 7)) * 16) = v;
        }
        asm volatile("s_waitcnt lgkmcnt(0)" ::: "memory");   // writes visible
        __builtin_amdgcn_sched_barrier(0);
        #pragma unroll
        for (int s = 0; s < 8; ++s) {
            int rho = s * 2 + (lane >> 5);
            int u = lane & 31, n4 = u * 4;
            if (n_base + n4 < 3136) {
                floatx4 v = *(const floatx4*)(Ew + rho * 512 + ((u ^ (rho & 7)) * 16));
                int o = o_base + it * 16 + rho;
                __builtin_nontemporal_store(v,
                    (floatx4*)(zb + (size_t)o * 3136 + n_base + n4));
            }
        }
        asm volatile("s_waitcnt lgkmcnt(0)" ::: "memory");   // reads done before
        __builtin_amdgcn_sched_barrier(0);                   // next it's writes
    }
}

extern "C" void kernel_launch(void* const* d_in, const int* in_sizes, int n_in,
                              void* d_out, int out_size, void* d_ws, size_t ws_size,
                              hipStream_t stream) {
    const float* x    = (const float*)d_in[0];
    const float* dw_w = (const float*)d_in[1];
    const float* dw_b = (const float*)d_in[2];
    const float* g1   = (const float*)d_in[3];
    const float* b1   = (const float*)d_in[4];
    const float* m1   = (const float*)d_in[5];
    const float* v1   = (const float*)d_in[6];
    const float* pw_w = (const float*)d_in[7];
    const float* pw_b = (const float*)d_in[8];
    const float* g2   = (const float*)d_in[9];
    const float* b2   = (const float*)d_in[10];
    const float* m2   = (const float*)d_in[11];
    const float* v2   = (const float*)d_in[12];
    float* z = (float*)d_out;

    // ws layout: y bf16 51,380,224 B | w_bf 65,536 B | bias2 1,024 B | keep 32,768 B
    const size_t YB = 51380224;
    unsigned short* y_ws = (unsigned short*)d_ws;
    unsigned short* w_bf = (unsigned short*)((char*)d_ws + YB);
    float* bias2         = (float*)((char*)d_ws + YB + 65536);
    float* keep          = (float*)((char*)d_ws + YB + 65536 + 1024);

    hipLaunchKernelGGL(k_dw, dim3(128, 64), dim3(256), 0, stream,
                       x, dw_w, dw_b, g1, b1, m1, v1,
                       pw_w, pw_b, g2, b2, m2, v2, y_ws, w_bf, bias2, keep);
    hipLaunchKernelGGL(k_pw, dim3(25, 64, 2), dim3(256), 0, stream,
                       y_ws, w_bf, bias2, keep, z);
}

// Round 9
// 310.663 us; speedup vs baseline: 1.0506x; 1.0104x over previous
//
#include <hip/hip_runtime.h>
#include <stdint.h>

#define EPSV 1e-5f

typedef __attribute__((ext_vector_type(8))) short short8;
typedef __attribute__((ext_vector_type(4))) float floatx4;
typedef __attribute__((ext_vector_type(2))) float float2v;

__device__ __forceinline__ unsigned short f2bf(float f) {
    union { float f; uint32_t u; } v; v.f = f;
    uint32_t u = v.u;
    return (unsigned short)((u + 0x7FFFu + ((u >> 16) & 1u)) >> 16);  // RNE
}

// ---- kernel 1: depthwise 3x3 + BN1 + ReLU + exact fp32 prune -> y bf16 [b][c][n]
//      (byte-identical to rounds 5/8 — attribution isolation)
__global__ __launch_bounds__(256) void k_dw(
        const float* __restrict__ x, const float* __restrict__ dw_w,
        const float* __restrict__ dw_b, const float* __restrict__ g1,
        const float* __restrict__ b1, const float* __restrict__ m1,
        const float* __restrict__ v1,
        const float* __restrict__ pw_w, const float* __restrict__ pw_b,
        const float* __restrict__ g2, const float* __restrict__ b2,
        const float* __restrict__ m2, const float* __restrict__ v2,
        unsigned short* __restrict__ y_ws,
        unsigned short* __restrict__ w_bf, float* __restrict__ bias2,
        float* __restrict__ keep) {
    const int c = blockIdx.x, b = blockIdx.y;
    const int t = threadIdx.x;
    __shared__ __align__(16) float halo_buf[4 + 58 * 60];  // 4-float front pad
    __shared__ float red[4];
    float* halo = halo_buf + 4;

    if (b == 0) {   // fused weight-fold with K-slot permutation
        int idx = c * 256 + t;
        int o = idx >> 7, s = idx & 127;
        int csrc = ((s >> 5) << 2) + ((s >> 3) & 3) + ((s & 7) << 4);
        float inv = g2[o] / sqrtf(v2[o] + EPSV);
        w_bf[idx] = f2bf(pw_w[o * 128 + csrc] * inv);
        if (s == 0) bias2[o] = pw_b[o] * inv + b2[o] - m2[o] * inv;
    }

    const float* xs = x + (size_t)(b * 128 + c) * 3136;

    {
        floatx4 zz = {0.f, 0.f, 0.f, 0.f};
        if (t < 15)       *(floatx4*)(halo + 4 * t) = zz;                  // row 0
        else if (t < 30)  *(floatx4*)(halo + 57 * 60 + 4 * (t - 15)) = zz; // row 57
        else if (t < 86)  *(floatx4*)(halo + (t - 29) * 60 + 56) = zz;     // right pad
        else if (t == 86) *(floatx4*)halo_buf = zz;                        // front pad
    }
    {
        const floatx4* x4 = (const floatx4*)xs;
        #pragma unroll
        for (int i = 0; i < 4; ++i) {
            int f = t + 256 * i;
            if (f < 784) {
                floatx4 v = x4[f];
                int p = 4 * f;
                int h = p / 56, ww = p - h * 56;
                *(floatx4*)(halo + (h + 1) * 60 + ww) = v;   // 16B aligned
            }
        }
    }
    const float* wk = dw_w + c * 9;
    float k0 = wk[0], k1 = wk[1], k2 = wk[2], k3 = wk[3], k4 = wk[4],
          k5 = wk[5], k6 = wk[6], k7 = wk[7], k8 = wk[8];
    float inv1 = g1[c] / sqrtf(v1[c] + EPSV);                 // exact, matches ref
    float add0 = dw_b[c] * inv1 + b1[c] - m1[c] * inv1;
    __syncthreads();

    float yv[16];
    float mx = 0.f;
    #pragma unroll
    for (int gi = 0; gi < 2; ++gi) {
        int g = t + gi * 256;
        if (g < 392) {
            int gh = g / 7, gw = (g - gh * 7) * 8;
            const float* p0 = halo + gh * 60 + gw;
            float w0[10], w1[10], w2[10];
#define LOADROW(dst, p) { \
            float2v L_ = *(const float2v*)((p) - 2); \
            floatx4 M0_ = *(const floatx4*)(p); \
            floatx4 M1_ = *(const floatx4*)((p) + 4); \
            float2v R_ = *(const float2v*)((p) + 8); \
            dst[0] = L_[1]; \
            dst[1] = M0_[0]; dst[2] = M0_[1]; dst[3] = M0_[2]; dst[4] = M0_[3]; \
            dst[5] = M1_[0]; dst[6] = M1_[1]; dst[7] = M1_[2]; dst[8] = M1_[3]; \
            dst[9] = R_[0]; }
            LOADROW(w0, p0)
            LOADROW(w1, p0 + 60)
            LOADROW(w2, p0 + 120)
#undef LOADROW
            #pragma unroll
            for (int j = 0; j < 8; ++j) {
                float s = k0 * w0[j] + k1 * w0[j + 1] + k2 * w0[j + 2]
                        + k3 * w1[j] + k4 * w1[j + 1] + k5 * w1[j + 2]
                        + k6 * w2[j] + k7 * w2[j + 1] + k8 * w2[j + 2];
                float yy = fmaxf(s * inv1 + add0, 0.f);
                mx = fmaxf(mx, yy);
                yv[gi * 8 + j] = yy;
            }
        }
    }
    #pragma unroll
    for (int off = 32; off; off >>= 1) mx = fmaxf(mx, __shfl_xor(mx, off));
    if ((t & 63) == 0) red[t >> 6] = mx;
    __syncthreads();
    float m4 = fmaxf(fmaxf(red[0], red[1]), fmaxf(red[2], red[3]));
    const bool kept = (m4 >= 4.0f);           // DW_THR, exact fp32 decision

    if (t == 0) keep[b * 128 + c] = kept ? 1.f : 0.f;

    if (kept) {                               // block-uniform: skip stores+pack
        unsigned short* yo = y_ws + (size_t)(b * 128 + c) * 3136;
        #pragma unroll
        for (int gi = 0; gi < 2; ++gi) {
            int g = t + gi * 256;
            if (g < 392) {
                uint4 pkv;
                uint32_t pk[4];
                #pragma unroll
                for (int j2 = 0; j2 < 4; ++j2) {
                    unsigned short h0 = f2bf(yv[gi * 8 + 2 * j2]);
                    unsigned short h1 = f2bf(yv[gi * 8 + 2 * j2 + 1]);
                    pk[j2] = (uint32_t)h0 | ((uint32_t)h1 << 16);
                }
                pkv.x = pk[0]; pkv.y = pk[1]; pkv.z = pk[2]; pkv.w = pk[3];
                *(uint4*)(yo + g * 8) = pkv;   // 16B aligned, lanes contiguous
            }
        }
    }
}

// ---- kernel 2: pointwise GEMM, operand-swapped mfma(A=y_frag, B=w_frag).
//      OCCUPANCY STEP 2: per-wave tile 16 o x 128 n (acc 32 VGPR, wf 16),
//      o-range split across blockIdx.z in quarters (grid 25 x 64 x 4).
//      Est. peak ~105 VGPR -> 4 waves/SIMD; LDS 36.9KB -> 4 blocks/CU
//      (+33% resident waves vs round 8's 3). Staging/MFMA/epilogue logic
//      otherwise identical to the round-8 proven code.
__global__ __launch_bounds__(256) void k_pw(
        const unsigned short* __restrict__ y,     // [b][c][3136] bf16
        const unsigned short* __restrict__ w_bf,  // [o][s] bf16, K-permuted
        const float* __restrict__ bias2, const float* __restrict__ keep,
        float* __restrict__ z) {
    const int nt = blockIdx.x;   // 25 N-tiles of 128 (last is half)
    const int b  = blockIdx.y;   // 64 batches
    const int oq = blockIdx.z;   // o-quarter: [oq*64, oq*64+64)
    const int t = threadIdx.x;
    const int w = t >> 6, lane = t & 63;
    const int q = lane >> 4, r = lane & 15;
    __shared__ __align__(16) char smem[36864];    // B_s, then reused as E
    short* B_s = (short*)smem;

    // stage: thread t loads y[c = t>>4 + 16i][nb..nb+8), nb=(t&15)*8 (coalesced),
    // register-transposes to W[j] = {y[t>>4 + 16e][nb+j]}, writes b128.
    // Layout: B_s[n][slot'][e], pitch 144 shorts; slot' = slot ^ (n>>3).
    {
        const int n0g = nt * 128;
        const int nb = (t & 15) * 8;
        const bool valid = (n0g + nb < 3136);      // chunks fully valid or out
        const float* kb = keep + b * 128;
        uint32_t Vd[8][4];
        const unsigned short* yb = y + (size_t)(b * 128) * 3136 + n0g + nb;
        #pragma unroll
        for (int i = 0; i < 8; ++i) {
            int cc = (t >> 4) + i * 16;
            uint4 v = make_uint4(0u, 0u, 0u, 0u);
            if (valid && kb[cc] != 0.f)            // pruned plane: keep zeros,
                v = *(const uint4*)(yb + (size_t)cc * 3136);  // never touch poison
            Vd[i][0] = v.x; Vd[i][1] = v.y; Vd[i][2] = v.z; Vd[i][3] = v.w;
        }
        const int slot_w = (t >> 4) ^ (t & 15);    // ^ (n>>3), n>>3 == t&15
        #pragma unroll
        for (int j = 0; j < 8; ++j) {
            const int sh = (j & 1) * 16;
            uint32_t Wd[4];
            #pragma unroll
            for (int k2 = 0; k2 < 4; ++k2) {
                uint32_t lo = (Vd[2 * k2][j >> 1] >> sh) & 0xffffu;
                uint32_t hi = (Vd[2 * k2 + 1][j >> 1] >> sh) & 0xffffu;
                Wd[k2] = lo | (hi << 16);
            }
            uint4 wv; wv.x = Wd[0]; wv.y = Wd[1]; wv.z = Wd[2]; wv.w = Wd[3];
            *(uint4*)&B_s[(nb + j) * 144 + slot_w * 8] = wv;
        }
    }

    // weight fragments (B operand), loaded after staging to cut peak VGPR:
    // wave w owns o in [oq*64 + w*16, +16); slot j holds w[o][c=kk*4+q+16j]
    const int o_base = oq * 64 + w * 16;
    short8 wf[4];
    #pragma unroll
    for (int kk = 0; kk < 4; ++kk)
        wf[kk] = *(const short8*)(w_bf +
            (size_t)(o_base + r) * 128 + kk * 32 + q * 8);

    __syncthreads();

    floatx4 acc[8];
    #pragma unroll
    for (int j = 0; j < 8; ++j) acc[j] = (floatx4)0.f;

    #pragma unroll
    for (int kk = 0; kk < 4; ++kk) {               // K = 128 = 4 x 32
        short8 yf[8];                              // A operand: y[n][c] frags
        #pragma unroll
        for (int jt = 0; jt < 8; ++jt) {
            int nl = jt * 16 + r;
            int slot_r = (kk * 4 + q) ^ (nl >> 3);
            yf[jt] = *(const short8*)&B_s[nl * 144 + slot_r * 8];
        }
        #pragma unroll
        for (int jt = 0; jt < 8; ++jt)
            acc[jt] = __builtin_amdgcn_mfma_f32_16x16x32_bf16(
                yf[jt], wf[kk], acc[jt], 0, 0, 0);
    }

    // epilogue: restage via wave-private LDS (writer: row r, unit u=4*jt+q,
    // swizzle u^(r&7); reader: half-wave per row rho, 512B-contiguous stores).
    __syncthreads();                               // B_s dead -> reuse as E
    char* Ew = smem + w * 8192;                    // wave-private 16 x 512B
    const int n_base = nt * 128;
    float* zb = z + (size_t)b * 256 * 3136;
    {
        float bv = bias2[o_base + r];
        #pragma unroll
        for (int jt = 0; jt < 8; ++jt) {
            floatx4 v;
            v[0] = fmaxf(acc[jt][0] + bv, 0.f);
            v[1] = fmaxf(acc[jt][1] + bv, 0.f);
            v[2] = fmaxf(acc[jt][2] + bv, 0.f);
            v[3] = fmaxf(acc[jt][3] + bv, 0.f);
            *(floatx4*)(Ew + r * 512 + ((4 * jt + q) ^ (r & 7)) * 16) = v;
        }
        asm volatile("s_waitcnt lgkmcnt(0)" ::: "memory");   // writes visible
        __builtin_amdgcn_sched_barrier(0);
        #pragma unroll
        for (int s = 0; s < 8; ++s) {
            int rho = s * 2 + (lane >> 5);
            int u = lane & 31, n4 = u * 4;
            if (n_base + n4 < 3136) {
                floatx4 v = *(const floatx4*)(Ew + rho * 512 + ((u ^ (rho & 7)) * 16));
                int o = o_base + rho;
                __builtin_nontemporal_store(v,
                    (floatx4*)(zb + (size_t)o * 3136 + n_base + n4));
            }
        }
    }
}

extern "C" void kernel_launch(void* const* d_in, const int* in_sizes, int n_in,
                              void* d_out, int out_size, void* d_ws, size_t ws_size,
                              hipStream_t stream) {
    const float* x    = (const float*)d_in[0];
    const float* dw_w = (const float*)d_in[1];
    const float* dw_b = (const float*)d_in[2];
    const float* g1   = (const float*)d_in[3];
    const float* b1   = (const float*)d_in[4];
    const float* m1   = (const float*)d_in[5];
    const float* v1   = (const float*)d_in[6];
    const float* pw_w = (const float*)d_in[7];
    const float* pw_b = (const float*)d_in[8];
    const float* g2   = (const float*)d_in[9];
    const float* b2   = (const float*)d_in[10];
    const float* m2   = (const float*)d_in[11];
    const float* v2   = (const float*)d_in[12];
    float* z = (float*)d_out;

    // ws layout: y bf16 51,380,224 B | w_bf 65,536 B | bias2 1,024 B | keep 32,768 B
    const size_t YB = 51380224;
    unsigned short* y_ws = (unsigned short*)d_ws;
    unsigned short* w_bf = (unsigned short*)((char*)d_ws + YB);
    float* bias2         = (float*)((char*)d_ws + YB + 65536);
    float* keep          = (float*)((char*)d_ws + YB + 65536 + 1024);

    hipLaunchKernelGGL(k_dw, dim3(128, 64), dim3(256), 0, stream,
                       x, dw_w, dw_b, g1, b1, m1, v1,
                       pw_w, pw_b, g2, b2, m2, v2, y_ws, w_bf, bias2, keep);
    hipLaunchKernelGGL(k_pw, dim3(25, 64, 4), dim3(256), 0, stream,
                       y_ws, w_bf, bias2, keep, z);
}